// Round 6
// baseline (253.877 us; speedup 1.0000x reference)
//
#include <hip/hip_runtime.h>

#define HID 40
#define RBKT 196          // buckets of 512 nodes: covers n <= 100352
#define BSH 9             // bucket shift (512 nodes per bucket)
#define CAP 12288         // per-bucket edge capacity (mean 8192, +45 sigma)
#define EPB 4096          // edges per block in binning pass

// ---------------- bf16 helpers ----------------

__device__ inline unsigned pack2_bf16(float a, float b) {
    unsigned ua = __float_as_uint(a);
    unsigned ub = __float_as_uint(b);
    ua = (ua + 0x7fffu + ((ua >> 16) & 1u)) >> 16;            // RNE, low half
    ub = (ub + 0x7fffu + ((ub >> 16) & 1u)) & 0xffff0000u;    // RNE, high half
    return ua | ub;
}

__device__ inline void acc8_bf16(float* acc, uint4 v) {
    acc[0] += __uint_as_float(v.x << 16);
    acc[1] += __uint_as_float(v.x & 0xffff0000u);
    acc[2] += __uint_as_float(v.y << 16);
    acc[3] += __uint_as_float(v.y & 0xffff0000u);
    acc[4] += __uint_as_float(v.z << 16);
    acc[5] += __uint_as_float(v.z & 0xffff0000u);
    acc[6] += __uint_as_float(v.w << 16);
    acc[7] += __uint_as_float(v.w & 0xffff0000u);
}

// zero bucket_cnt[RBKT] and g_sum[G] in one tiny dispatch
__global__ void clear_kernel(int* __restrict__ bucket_cnt, float* __restrict__ g_sum, int G) {
    int t = blockIdx.x * blockDim.x + threadIdx.x;
    if (t < RBKT) bucket_cnt[t] = 0;
    if (t < G) g_sum[t] = 0.f;
}

// ---------------- CSR build (two-level bucketed) ----------------

__global__ __launch_bounds__(256) void binA_kernel(
        const int* __restrict__ esrc, const int* __restrict__ edst, int E,
        int* __restrict__ bucket_cnt, int* __restrict__ bucket_data) {
    __shared__ int cnt_l[RBKT];
    __shared__ int base_l[RBKT];
    int t = threadIdx.x;
    for (int b = t; b < RBKT; b += 256) cnt_l[b] = 0;
    __syncthreads();
    int e0 = blockIdx.x * EPB;
    int e1 = min(e0 + EPB, E);
    for (int e = e0 + t; e < e1; e += 256) {
        atomicAdd(&cnt_l[edst[e] >> BSH], 1);
    }
    __syncthreads();
    for (int b = t; b < RBKT; b += 256) {
        int c = cnt_l[b];
        base_l[b] = (c > 0) ? atomicAdd(&bucket_cnt[b], c) : 0;
        cnt_l[b] = 0;
    }
    __syncthreads();
    for (int e = e0 + t; e < e1; e += 256) {
        int d = edst[e];
        int s = esrc[e];
        int b = d >> BSH;
        int off = base_l[b] + atomicAdd(&cnt_l[b], 1);
        if (off < CAP) bucket_data[(size_t)b * CAP + off] = (s << BSH) | (d & 511);
    }
}

__global__ void scan_buckets_kernel(const int* __restrict__ cnt, int* __restrict__ base) {
    __shared__ int s[256];
    int t = threadIdx.x;
    int c = (t < RBKT) ? min(cnt[t], CAP) : 0;
    s[t] = c;
    __syncthreads();
    for (int off = 1; off < 256; off <<= 1) {
        int y = (t >= off) ? s[t - off] : 0;
        __syncthreads();
        s[t] += y;
        __syncthreads();
    }
    if (t < RBKT) base[t] = s[t] - c;
    if (t == RBKT - 1) base[RBKT] = s[t];
}

__global__ __launch_bounds__(256) void buildB_kernel(
        const int* __restrict__ bucket_cnt, const int* __restrict__ bucket_base,
        const int* __restrict__ bucket_data,
        int* __restrict__ rowptr, int* __restrict__ csr,
        float* __restrict__ dinv, int n) {
    __shared__ int deg_l[512];
    __shared__ int off_l[512];
    __shared__ int ps[256];
    int r = blockIdx.x;
    int t = threadIdx.x;
    int cnt = min(bucket_cnt[r], CAP);
    int base = bucket_base[r];
    int node0 = r << BSH;
    int nr = min(512, n - node0);
    for (int i = t; i < 512; i += 256) deg_l[i] = 0;
    __syncthreads();
    const int* data = bucket_data + (size_t)r * CAP;
    for (int e = t; e < cnt; e += 256) atomicAdd(&deg_l[data[e] & 511], 1);
    __syncthreads();
    int a0 = deg_l[2 * t], a1 = deg_l[2 * t + 1];
    ps[t] = a0 + a1;
    __syncthreads();
    for (int off = 1; off < 256; off <<= 1) {
        int y = (t >= off) ? ps[t - off] : 0;
        __syncthreads();
        ps[t] += y;
        __syncthreads();
    }
    int excl = ps[t] - (a0 + a1);
    off_l[2 * t] = excl;
    off_l[2 * t + 1] = excl + a0;
    __syncthreads();
    for (int i = t; i < nr; i += 256) {
        rowptr[node0 + i] = base + off_l[i];
        dinv[node0 + i] = rsqrtf((float)(deg_l[i] + 1));
    }
    if (r == RBKT - 1 && t == 0) rowptr[n] = base + cnt;
    __syncthreads();
    for (int e = t; e < cnt; e += 256) {
        int v = data[e];
        int p = atomicAdd(&off_l[v & 511], 1);
        csr[base + p] = v >> BSH;
    }
}

// ---------------- layer kernels ----------------

// x (f32, n x 30) * dinv -> bf16 table, 16 uints/row (32 bf16 slots, last 2 zero)
__global__ __launch_bounds__(256) void scale_bf16_kernel(
        const float* __restrict__ x, const float* __restrict__ dinv,
        unsigned* __restrict__ xs, int n) {
    int t = blockIdx.x * blockDim.x + threadIdx.x;
    int i = t >> 4, p = t & 15;
    if (i >= n) return;
    float a = 0.f, b = 0.f;
    if (p < 15) {
        float d = dinv[i];
        a = x[i * 30 + 2 * p] * d;
        b = x[i * 30 + 2 * p + 1] * d;
    }
    xs[(size_t)i * 16 + p] = pack2_bf16(a, b);
}

// bf16 gather -> bf16 out (dinv-scaled). Row = TPN uint4s. TPN threads/node.
template <int TPN>
__global__ __launch_bounds__(256) void gather_bf16_kernel(
        const unsigned* __restrict__ xs, const int* __restrict__ rowptr,
        const int* __restrict__ csr, const float* __restrict__ dinv,
        unsigned* __restrict__ gout, int n) {
    int t = blockIdx.x * blockDim.x + threadIdx.x;
    int i = t / TPN;
    int q = t - i * TPN;
    if (i >= n) return;
    const uint4* tab = reinterpret_cast<const uint4*>(xs);
    float acc[8];
    {
        uint4 v = tab[(size_t)i * TPN + q];        // self loop
        acc[0] = __uint_as_float(v.x << 16);
        acc[1] = __uint_as_float(v.x & 0xffff0000u);
        acc[2] = __uint_as_float(v.y << 16);
        acc[3] = __uint_as_float(v.y & 0xffff0000u);
        acc[4] = __uint_as_float(v.z << 16);
        acc[5] = __uint_as_float(v.z & 0xffff0000u);
        acc[6] = __uint_as_float(v.w << 16);
        acc[7] = __uint_as_float(v.w & 0xffff0000u);
    }
    int e0 = rowptr[i], e1 = rowptr[i + 1];
    int e = e0;
    for (; e + 4 <= e1; e += 4) {                  // 4-way unroll: 4 loads in flight
        int s0 = csr[e], s1 = csr[e + 1], s2 = csr[e + 2], s3 = csr[e + 3];
        uint4 v0 = tab[(size_t)s0 * TPN + q];
        uint4 v1 = tab[(size_t)s1 * TPN + q];
        uint4 v2 = tab[(size_t)s2 * TPN + q];
        uint4 v3 = tab[(size_t)s3 * TPN + q];
        acc8_bf16(acc, v0);
        acc8_bf16(acc, v1);
        acc8_bf16(acc, v2);
        acc8_bf16(acc, v3);
    }
    for (; e < e1; e++) {
        int s0 = csr[e];
        acc8_bf16(acc, tab[(size_t)s0 * TPN + q]);
    }
    float d = dinv[i];
    uint4 o;
    o.x = pack2_bf16(acc[0] * d, acc[1] * d);
    o.y = pack2_bf16(acc[2] * d, acc[3] * d);
    o.z = pack2_bf16(acc[4] * d, acc[5] * d);
    o.w = pack2_bf16(acc[6] * d, acc[7] * d);
    reinterpret_cast<uint4*>(gout)[(size_t)i * TPN + q] = o;
}

// Transform: reads packed-bf16 rows (RU uints/node) via coalesced LDS staging,
// y[i,f] = relu(sum_k t[i,k] W[k,f] + b[f]) * dinv[i] packed bf16, 20 uints/row.
template <int IN, int RU>
__global__ __launch_bounds__(256) void transform_bf16_kernel(
        const unsigned* __restrict__ tin, const float* __restrict__ W,
        const float* __restrict__ bias, const float* __restrict__ dinv,
        unsigned* __restrict__ out, int n) {
    __shared__ float Ws[IN * HID];
    __shared__ unsigned tile[256 * (RU + 1)];
    for (int t = threadIdx.x; t < IN * HID; t += blockDim.x) Ws[t] = W[t];
    int base = blockIdx.x * 256;
    const unsigned* g = tin + (size_t)base * RU;
    int tid = threadIdx.x;
    #pragma unroll
    for (int j = 0; j < RU; j++) {
        int idx = j * 256 + tid;
        int row = idx / RU, col = idx - row * RU;
        if (base + row < n) tile[row * (RU + 1) + col] = g[idx];
    }
    __syncthreads();
    int i = base + tid;
    if (i >= n) return;
    const unsigned* myrow = &tile[tid * (RU + 1)];
    float xr[IN];
    #pragma unroll
    for (int j = 0; j < IN / 2; j++) {
        unsigned u = myrow[j];
        xr[2 * j]     = __uint_as_float(u << 16);
        xr[2 * j + 1] = __uint_as_float(u & 0xffff0000u);
    }
    float acc[HID];
    #pragma unroll
    for (int f = 0; f < HID; f++) acc[f] = 0.f;
    #pragma unroll
    for (int k = 0; k < IN; k++) {
        #pragma unroll
        for (int j = 0; j < HID / 4; j++) {
            float4 w4 = *reinterpret_cast<const float4*>(&Ws[k * HID + j * 4]);
            acc[j * 4 + 0] += xr[k] * w4.x;
            acc[j * 4 + 1] += xr[k] * w4.y;
            acc[j * 4 + 2] += xr[k] * w4.z;
            acc[j * 4 + 3] += xr[k] * w4.w;
        }
    }
    float scale = dinv[i];
    uint4 u[5];
    unsigned* up = reinterpret_cast<unsigned*>(u);
    #pragma unroll
    for (int j = 0; j < HID / 2; j++) {
        float v0 = fmaxf(acc[2 * j] + bias[2 * j], 0.f) * scale;
        float v1 = fmaxf(acc[2 * j + 1] + bias[2 * j + 1], 0.f) * scale;
        up[j] = pack2_bf16(v0, v1);
    }
    uint4* ob = reinterpret_cast<uint4*>(out + (size_t)i * 20);
    #pragma unroll
    for (int j = 0; j < 5; j++) ob[j] = u[j];
}

// Layer-3 transform fused with mean-pool + linear (LDS-staged input).
template <int IN, int RU>
__global__ __launch_bounds__(256) void transform_pool_kernel(
        const unsigned* __restrict__ tin, const float* __restrict__ W,
        const float* __restrict__ bias, const float* __restrict__ lin_w,
        const int* __restrict__ batch, float* __restrict__ g_sum, int n) {
    __shared__ float Ws[IN * HID];
    __shared__ float lw[HID];
    __shared__ unsigned tile[256 * (RU + 1)];
    for (int t = threadIdx.x; t < IN * HID; t += blockDim.x) Ws[t] = W[t];
    for (int t = threadIdx.x; t < HID; t += blockDim.x) lw[t] = lin_w[t];
    int base = blockIdx.x * 256;
    const unsigned* g = tin + (size_t)base * RU;
    int tid = threadIdx.x;
    #pragma unroll
    for (int j = 0; j < RU; j++) {
        int idx = j * 256 + tid;
        int row = idx / RU, col = idx - row * RU;
        if (base + row < n) tile[row * (RU + 1) + col] = g[idx];
    }
    __syncthreads();
    int i0 = base + tid;
    bool valid = (i0 < n);
    int i = valid ? i0 : (n - 1);
    float s = 0.f;
    if (valid) {
        const unsigned* myrow = &tile[tid * (RU + 1)];
        float xr[IN];
        #pragma unroll
        for (int j = 0; j < IN / 2; j++) {
            unsigned u = myrow[j];
            xr[2 * j]     = __uint_as_float(u << 16);
            xr[2 * j + 1] = __uint_as_float(u & 0xffff0000u);
        }
        float acc[HID];
        #pragma unroll
        for (int f = 0; f < HID; f++) acc[f] = 0.f;
        #pragma unroll
        for (int k = 0; k < IN; k++) {
            #pragma unroll
            for (int j = 0; j < HID / 4; j++) {
                float4 w4 = *reinterpret_cast<const float4*>(&Ws[k * HID + j * 4]);
                acc[j * 4 + 0] += xr[k] * w4.x;
                acc[j * 4 + 1] += xr[k] * w4.y;
                acc[j * 4 + 2] += xr[k] * w4.z;
                acc[j * 4 + 3] += xr[k] * w4.w;
            }
        }
        #pragma unroll
        for (int f = 0; f < HID; f++) s += fmaxf(acc[f] + bias[f], 0.f) * lw[f];
    }
    int gidx = batch[i];
    int g0 = __shfl(gidx, 0, 64);
    if (__all(gidx == g0)) {
        #pragma unroll
        for (int off = 32; off > 0; off >>= 1) s += __shfl_xor(s, off, 64);
        if ((threadIdx.x & 63) == 0) atomicAdd(&g_sum[g0], s);
    } else {
        if (valid) atomicAdd(&g_sum[gidx], s);
    }
}

__global__ void finalize_kernel(const float* __restrict__ g_sum,
                                const int* __restrict__ batch,
                                const float* __restrict__ lin_b,
                                float* __restrict__ out, int n, int G) {
    int b = blockIdx.x * blockDim.x + threadIdx.x;
    if (b >= G) return;
    int lo = 0, hi = n;
    while (lo < hi) { int m = (lo + hi) >> 1; if (batch[m] < b) lo = m + 1; else hi = m; }
    int lo2 = lo, hi2 = n;
    while (lo2 < hi2) { int m = (lo2 + hi2) >> 1; if (batch[m] < b + 1) lo2 = m + 1; else hi2 = m; }
    int cnt = lo2 - lo;
    out[b] = g_sum[b] / (float)(cnt > 0 ? cnt : 1) + lin_b[0];
}

// ---------------- launch ----------------

static inline size_t align_up(size_t v, size_t a) { return (v + a - 1) / a * a; }

extern "C" void kernel_launch(void* const* d_in, const int* in_sizes, int n_in,
                              void* d_out, int out_size, void* d_ws, size_t ws_size,
                              hipStream_t stream) {
    const float* x      = (const float*)d_in[0];
    const int*   esrc   = (const int*)d_in[1];
    const int*   batch  = (const int*)d_in[2];
    const float* W1     = (const float*)d_in[3];
    const float* b1     = (const float*)d_in[4];
    const float* W2     = (const float*)d_in[5];
    const float* b2     = (const float*)d_in[6];
    const float* W3     = (const float*)d_in[7];
    const float* b3     = (const float*)d_in[8];
    const float* lin_w  = (const float*)d_in[9];
    const float* lin_b  = (const float*)d_in[10];
    float* out = (float*)d_out;

    const int n = in_sizes[0] / 30;
    const int E = in_sizes[1] / 2;
    const int G = out_size;
    const int* edst = esrc + E;

    char* w = (char*)d_ws;
    size_t off = 0;
    auto take = [&](size_t bytes) { size_t o = off; off = align_up(off + bytes, 256); return (void*)(w + o); };
    int*      bucket_cnt  = (int*)take((size_t)RBKT * 4);
    int*      bucket_base = (int*)take((size_t)(RBKT + 1) * 4);
    int*      rowptr      = (int*)take((size_t)(n + 1) * 4);
    float*    dinv        = (float*)take((size_t)n * 4);
    int*      csr         = (int*)take((size_t)E * 4);
    float*    g_sum       = (float*)take((size_t)G * 4);
    // bucket_data (9.6 MB) dead after buildB; alias with xs1 (6.4 MB)
    size_t bd = (size_t)RBKT * CAP * 4;
    size_t x1 = (size_t)n * 16 * 4;
    void* shared_region = take(bd > x1 ? bd : x1);
    int*      bucket_data = (int*)shared_region;
    unsigned* xs1         = (unsigned*)shared_region;
    unsigned* tb          = (unsigned*)take((size_t)n * 20 * 4);  // 20-uint bf16 rows
    unsigned* agg         = (unsigned*)take((size_t)n * 20 * 4);  // gather output (16/20-uint rows)
    (void)ws_size;

    clear_kernel<<<1, 256, 0, stream>>>(bucket_cnt, g_sum, G);

    binA_kernel<<<(E + EPB - 1) / EPB, 256, 0, stream>>>(esrc, edst, E, bucket_cnt, bucket_data);
    scan_buckets_kernel<<<1, 256, 0, stream>>>(bucket_cnt, bucket_base);
    buildB_kernel<<<RBKT, 256, 0, stream>>>(bucket_cnt, bucket_base, bucket_data,
                                            rowptr, csr, dinv, n);

    int ngrid_n = (n + 255) / 256;

    // layer 1: 16-uint rows, 4 threads/node
    scale_bf16_kernel<<<((size_t)n * 16 + 255) / 256, 256, 0, stream>>>(x, dinv, xs1, n);
    gather_bf16_kernel<4><<<((size_t)n * 4 + 255) / 256, 256, 0, stream>>>(
        xs1, rowptr, csr, dinv, agg, n);
    transform_bf16_kernel<30, 16><<<ngrid_n, 256, 0, stream>>>(agg, W1, b1, dinv, tb, n);
    // layer 2: 20-uint rows, 5 threads/node
    gather_bf16_kernel<5><<<((size_t)n * 5 + 255) / 256, 256, 0, stream>>>(
        tb, rowptr, csr, dinv, agg, n);
    transform_bf16_kernel<40, 20><<<ngrid_n, 256, 0, stream>>>(agg, W2, b2, dinv, tb, n);
    // layer 3 + fused pool/linear
    gather_bf16_kernel<5><<<((size_t)n * 5 + 255) / 256, 256, 0, stream>>>(
        tb, rowptr, csr, dinv, agg, n);
    transform_pool_kernel<40, 20><<<ngrid_n, 256, 0, stream>>>(agg, W3, b3, lin_w, batch, g_sum, n);

    finalize_kernel<<<1, 256, 0, stream>>>(g_sum, batch, lin_b, out, n, G);
}

// Round 7
// 216.125 us; speedup vs baseline: 1.1747x; 1.1747x over previous
//
#include <hip/hip_runtime.h>

#define HID 40
#define RBKT 196          // buckets of 512 nodes: covers n <= 100352
#define BSH 9             // bucket shift (512 nodes per bucket)
#define CAP 12288         // per-bucket edge capacity (mean 8192, +45 sigma)
#define EPB 4096          // edges per block in binning pass

// ---------------- bf16 helpers ----------------

__device__ inline unsigned pack2_bf16(float a, float b) {
    unsigned ua = __float_as_uint(a);
    unsigned ub = __float_as_uint(b);
    ua = (ua + 0x7fffu + ((ua >> 16) & 1u)) >> 16;            // RNE, low half
    ub = (ub + 0x7fffu + ((ub >> 16) & 1u)) & 0xffff0000u;    // RNE, high half
    return ua | ub;
}

__device__ inline void acc8_bf16(float* acc, uint4 v) {
    acc[0] += __uint_as_float(v.x << 16);
    acc[1] += __uint_as_float(v.x & 0xffff0000u);
    acc[2] += __uint_as_float(v.y << 16);
    acc[3] += __uint_as_float(v.y & 0xffff0000u);
    acc[4] += __uint_as_float(v.z << 16);
    acc[5] += __uint_as_float(v.z & 0xffff0000u);
    acc[6] += __uint_as_float(v.w << 16);
    acc[7] += __uint_as_float(v.w & 0xffff0000u);
}

__global__ void clear_kernel(int* __restrict__ bucket_cnt, float* __restrict__ g_sum, int G) {
    int t = blockIdx.x * blockDim.x + threadIdx.x;
    if (t < RBKT) bucket_cnt[t] = 0;
    if (t < G) g_sum[t] = 0.f;
}

// ---------------- CSR build (two-level bucketed) ----------------

__global__ __launch_bounds__(256) void binA_kernel(
        const int* __restrict__ esrc, const int* __restrict__ edst, int E,
        int* __restrict__ bucket_cnt, int* __restrict__ bucket_data) {
    __shared__ int cnt_l[RBKT];
    __shared__ int base_l[RBKT];
    int t = threadIdx.x;
    for (int b = t; b < RBKT; b += 256) cnt_l[b] = 0;
    __syncthreads();
    int e0 = blockIdx.x * EPB;
    int e1 = min(e0 + EPB, E);
    for (int e = e0 + t; e < e1; e += 256) {
        atomicAdd(&cnt_l[edst[e] >> BSH], 1);
    }
    __syncthreads();
    for (int b = t; b < RBKT; b += 256) {
        int c = cnt_l[b];
        base_l[b] = (c > 0) ? atomicAdd(&bucket_cnt[b], c) : 0;
        cnt_l[b] = 0;
    }
    __syncthreads();
    for (int e = e0 + t; e < e1; e += 256) {
        int d = edst[e];
        int s = esrc[e];
        int b = d >> BSH;
        int off = base_l[b] + atomicAdd(&cnt_l[b], 1);
        if (off < CAP) bucket_data[(size_t)b * CAP + off] = (s << BSH) | (d & 511);
    }
}

__global__ void scan_buckets_kernel(const int* __restrict__ cnt, int* __restrict__ base) {
    __shared__ int s[256];
    int t = threadIdx.x;
    int c = (t < RBKT) ? min(cnt[t], CAP) : 0;
    s[t] = c;
    __syncthreads();
    for (int off = 1; off < 256; off <<= 1) {
        int y = (t >= off) ? s[t - off] : 0;
        __syncthreads();
        s[t] += y;
        __syncthreads();
    }
    if (t < RBKT) base[t] = s[t] - c;
    if (t == RBKT - 1) base[RBKT] = s[t];
}

__global__ __launch_bounds__(256) void buildB_kernel(
        const int* __restrict__ bucket_cnt, const int* __restrict__ bucket_base,
        const int* __restrict__ bucket_data,
        int* __restrict__ rowptr, int* __restrict__ csr,
        float* __restrict__ dinv, int n) {
    __shared__ int deg_l[512];
    __shared__ int off_l[512];
    __shared__ int ps[256];
    int r = blockIdx.x;
    int t = threadIdx.x;
    int cnt = min(bucket_cnt[r], CAP);
    int base = bucket_base[r];
    int node0 = r << BSH;
    int nr = min(512, n - node0);
    for (int i = t; i < 512; i += 256) deg_l[i] = 0;
    __syncthreads();
    const int* data = bucket_data + (size_t)r * CAP;
    for (int e = t; e < cnt; e += 256) atomicAdd(&deg_l[data[e] & 511], 1);
    __syncthreads();
    int a0 = deg_l[2 * t], a1 = deg_l[2 * t + 1];
    ps[t] = a0 + a1;
    __syncthreads();
    for (int off = 1; off < 256; off <<= 1) {
        int y = (t >= off) ? ps[t - off] : 0;
        __syncthreads();
        ps[t] += y;
        __syncthreads();
    }
    int excl = ps[t] - (a0 + a1);
    off_l[2 * t] = excl;
    off_l[2 * t + 1] = excl + a0;
    __syncthreads();
    for (int i = t; i < nr; i += 256) {
        rowptr[node0 + i] = base + off_l[i];
        dinv[node0 + i] = rsqrtf((float)(deg_l[i] + 1));
    }
    if (r == RBKT - 1 && t == 0) rowptr[n] = base + cnt;
    __syncthreads();
    for (int e = t; e < cnt; e += 256) {
        int v = data[e];
        int p = atomicAdd(&off_l[v & 511], 1);
        csr[base + p] = v >> BSH;
    }
}

// ---------------- layer kernels ----------------

// x (f32, n x 30) * dinv -> bf16 table, 16 uints/row (32 slots, last 2 zero)
__global__ __launch_bounds__(256) void scale_bf16_kernel(
        const float* __restrict__ x, const float* __restrict__ dinv,
        unsigned* __restrict__ xs, int n) {
    int t = blockIdx.x * blockDim.x + threadIdx.x;
    int i = t >> 4, p = t & 15;
    if (i >= n) return;
    float a = 0.f, b = 0.f;
    if (p < 15) {
        float d = dinv[i];
        a = x[i * 30 + 2 * p] * d;
        b = x[i * 30 + 2 * p + 1] * d;
    }
    xs[(size_t)i * 16 + p] = pack2_bf16(a, b);
}

// Fused gather + transform (+ optional pool).
// 64 nodes/block, TPN threads/node. Input rows = TPN uint4s of bf16.
// Phase 1 (gather): thread (node,q) accumulates 8 features over neighbors, writes
//   f32 agg row slice to LDS. Phase 2 (transform): same thread computes
//   OPF = OUTF/TPN outputs from the LDS agg row + LDS weights.
// POOL=false: outputs packed bf16 (dinv-prescaled) to gout (OUTF/2 uints/row).
// POOL=true : s_i = sum_f relu(h)*lin_w[f], segment-summed into g_sum.
template <int INF, int TPN, int OUTF, bool POOL>
__global__ __launch_bounds__(64 * TPN) void fused_layer_kernel(
        const unsigned* __restrict__ xs, const int* __restrict__ rowptr,
        const int* __restrict__ csr, const float* __restrict__ dinv,
        const float* __restrict__ W, const float* __restrict__ bias,
        const float* __restrict__ lin_w, const int* __restrict__ batch,
        unsigned* __restrict__ gout, float* __restrict__ g_sum, int n) {
    constexpr int NT  = 64 * TPN;       // block threads
    constexpr int STR = 8 * TPN + 1;    // agg LDS row stride (floats)
    constexpr int OPF = OUTF / TPN;     // outputs per thread
    __shared__ float Ws[INF * OUTF];
    __shared__ float aggs[64 * STR];
    __shared__ float lw[POOL ? OUTF : 1];
    __shared__ float sarr[POOL ? NT : 1];
    const int tid = threadIdx.x;
    for (int t = tid; t < INF * OUTF; t += NT) Ws[t] = W[t];
    if (POOL) {
        for (int t = tid; t < OUTF; t += NT) lw[t] = lin_w[t];
    }
    const int node_l = tid / TPN, q = tid - node_l * TPN;
    const int node = blockIdx.x * 64 + node_l;
    const bool valid = (node < n);
    if (valid) {
        const uint4* tab = reinterpret_cast<const uint4*>(xs);
        float acc[8];
        {
            uint4 v = tab[(size_t)node * TPN + q];     // self loop
            acc[0] = __uint_as_float(v.x << 16);
            acc[1] = __uint_as_float(v.x & 0xffff0000u);
            acc[2] = __uint_as_float(v.y << 16);
            acc[3] = __uint_as_float(v.y & 0xffff0000u);
            acc[4] = __uint_as_float(v.z << 16);
            acc[5] = __uint_as_float(v.z & 0xffff0000u);
            acc[6] = __uint_as_float(v.w << 16);
            acc[7] = __uint_as_float(v.w & 0xffff0000u);
        }
        int e0 = rowptr[node], e1 = rowptr[node + 1];
        int e = e0;
        for (; e + 4 <= e1; e += 4) {
            int s0 = csr[e], s1 = csr[e + 1], s2 = csr[e + 2], s3 = csr[e + 3];
            uint4 v0 = tab[(size_t)s0 * TPN + q];
            uint4 v1 = tab[(size_t)s1 * TPN + q];
            uint4 v2 = tab[(size_t)s2 * TPN + q];
            uint4 v3 = tab[(size_t)s3 * TPN + q];
            acc8_bf16(acc, v0);
            acc8_bf16(acc, v1);
            acc8_bf16(acc, v2);
            acc8_bf16(acc, v3);
        }
        for (; e < e1; e++) {
            acc8_bf16(acc, tab[(size_t)csr[e] * TPN + q]);
        }
        float d = dinv[node];
        float* ar = &aggs[node_l * STR + q * 8];
        #pragma unroll
        for (int j = 0; j < 8; j++) ar[j] = acc[j] * d;
    }
    __syncthreads();
    if (POOL) sarr[tid] = 0.f;
    if (valid) {
        const float* arow = &aggs[node_l * STR];
        float acc2[OPF];
        #pragma unroll
        for (int j = 0; j < OPF; j++) acc2[j] = 0.f;
        for (int k = 0; k < INF; k++) {
            float xk = arow[k];
            #pragma unroll
            for (int j = 0; j < OPF; j++) acc2[j] += xk * Ws[k * OUTF + q * OPF + j];
        }
        if (!POOL) {
            float scale = dinv[node];
            unsigned* orow = gout + (size_t)node * (OUTF / 2) + q * (OPF / 2);
            #pragma unroll
            for (int j = 0; j < OPF / 2; j++) {
                int f = q * OPF + 2 * j;
                float v0 = fmaxf(acc2[2 * j] + bias[f], 0.f) * scale;
                float v1 = fmaxf(acc2[2 * j + 1] + bias[f + 1], 0.f) * scale;
                orow[j] = pack2_bf16(v0, v1);
            }
        } else {
            float s = 0.f;
            #pragma unroll
            for (int j = 0; j < OPF; j++) {
                int f = q * OPF + j;
                s += fmaxf(acc2[j] + bias[f], 0.f) * lw[f];
            }
            sarr[tid] = s;
        }
    }
    if (POOL) {
        __syncthreads();
        if (tid < 64) {
            float s = 0.f;
            #pragma unroll
            for (int q2 = 0; q2 < TPN; q2++) s += sarr[tid * TPN + q2];
            int node2 = blockIdx.x * 64 + tid;
            bool v2 = (node2 < n);
            int g = batch[v2 ? node2 : (n - 1)];
            if (!v2) s = 0.f;
            int g0 = __shfl(g, 0, 64);
            if (__all(g == g0)) {
                #pragma unroll
                for (int off = 32; off > 0; off >>= 1) s += __shfl_xor(s, off, 64);
                if (tid == 0) atomicAdd(&g_sum[g0], s);
            } else {
                if (v2) atomicAdd(&g_sum[g], s);
            }
        }
    }
}

__global__ void finalize_kernel(const float* __restrict__ g_sum,
                                const int* __restrict__ batch,
                                const float* __restrict__ lin_b,
                                float* __restrict__ out, int n, int G) {
    int b = blockIdx.x * blockDim.x + threadIdx.x;
    if (b >= G) return;
    int lo = 0, hi = n;
    while (lo < hi) { int m = (lo + hi) >> 1; if (batch[m] < b) lo = m + 1; else hi = m; }
    int lo2 = lo, hi2 = n;
    while (lo2 < hi2) { int m = (lo2 + hi2) >> 1; if (batch[m] < b + 1) lo2 = m + 1; else hi2 = m; }
    int cnt = lo2 - lo;
    out[b] = g_sum[b] / (float)(cnt > 0 ? cnt : 1) + lin_b[0];
}

// ---------------- launch ----------------

static inline size_t align_up(size_t v, size_t a) { return (v + a - 1) / a * a; }

extern "C" void kernel_launch(void* const* d_in, const int* in_sizes, int n_in,
                              void* d_out, int out_size, void* d_ws, size_t ws_size,
                              hipStream_t stream) {
    const float* x      = (const float*)d_in[0];
    const int*   esrc   = (const int*)d_in[1];
    const int*   batch  = (const int*)d_in[2];
    const float* W1     = (const float*)d_in[3];
    const float* b1     = (const float*)d_in[4];
    const float* W2     = (const float*)d_in[5];
    const float* b2     = (const float*)d_in[6];
    const float* W3     = (const float*)d_in[7];
    const float* b3     = (const float*)d_in[8];
    const float* lin_w  = (const float*)d_in[9];
    const float* lin_b  = (const float*)d_in[10];
    float* out = (float*)d_out;

    const int n = in_sizes[0] / 30;
    const int E = in_sizes[1] / 2;
    const int G = out_size;
    const int* edst = esrc + E;

    char* w = (char*)d_ws;
    size_t off = 0;
    auto take = [&](size_t bytes) { size_t o = off; off = align_up(off + bytes, 256); return (void*)(w + o); };
    int*      bucket_cnt  = (int*)take((size_t)RBKT * 4);
    int*      bucket_base = (int*)take((size_t)(RBKT + 1) * 4);
    int*      rowptr      = (int*)take((size_t)(n + 1) * 4);
    float*    dinv        = (float*)take((size_t)n * 4);
    int*      csr         = (int*)take((size_t)E * 4);
    float*    g_sum       = (float*)take((size_t)G * 4);
    // bucket_data (9.6 MB) dead after buildB; alias with xs1 (6.4 MB)
    size_t bd = (size_t)RBKT * CAP * 4;
    size_t x1 = (size_t)n * 16 * 4;
    void* shared_region = take(bd > x1 ? bd : x1);
    int*      bucket_data = (int*)shared_region;
    unsigned* xs1         = (unsigned*)shared_region;
    unsigned* tbA         = (unsigned*)take((size_t)n * 20 * 4);  // bf16 table (20 uints/row)
    unsigned* tbB         = (unsigned*)take((size_t)n * 20 * 4);
    (void)ws_size;

    clear_kernel<<<1, 256, 0, stream>>>(bucket_cnt, g_sum, G);

    binA_kernel<<<(E + EPB - 1) / EPB, 256, 0, stream>>>(esrc, edst, E, bucket_cnt, bucket_data);
    scan_buckets_kernel<<<1, 256, 0, stream>>>(bucket_cnt, bucket_base);
    buildB_kernel<<<RBKT, 256, 0, stream>>>(bucket_cnt, bucket_base, bucket_data,
                                            rowptr, csr, dinv, n);

    int nblk = (n + 63) / 64;

    // layer 1: 4 threads/node (16-uint rows), fused gather+transform 30->40
    scale_bf16_kernel<<<((size_t)n * 16 + 255) / 256, 256, 0, stream>>>(x, dinv, xs1, n);
    fused_layer_kernel<30, 4, HID, false><<<nblk, 256, 0, stream>>>(
        xs1, rowptr, csr, dinv, W1, b1, nullptr, nullptr, tbA, nullptr, n);
    // layer 2: 5 threads/node (20-uint rows), fused gather+transform 40->40
    fused_layer_kernel<HID, 5, HID, false><<<nblk, 320, 0, stream>>>(
        tbA, rowptr, csr, dinv, W2, b2, nullptr, nullptr, tbB, nullptr, n);
    // layer 3: fused gather+transform+pool+linear
    fused_layer_kernel<HID, 5, HID, true><<<nblk, 320, 0, stream>>>(
        tbB, rowptr, csr, dinv, W3, b3, lin_w, batch, nullptr, g_sum, n);

    finalize_kernel<<<1, 256, 0, stream>>>(g_sum, batch, lin_b, out, n, G);
}